// Round 1
// 112.026 us; speedup vs baseline: 1.1641x; 1.1641x over previous
//
#include <hip/hip_runtime.h>

// NTXentLoss, B=8192, D=128, T=0.1, idx=0. fp32 in, fp32 scalar out.
// R7: j-streaming restructure. Old: 4 K-phases x full barrier drain per
// 128x128 tile -> MfmaUtil 12%, latency-bound. New: A-slab (64 rows x K=128
// per wave) lives in 64 VGPRs; each block streams NJ=8 full-K B tiles
// (32 KB, double-buffered, pre-swizzled global_load_lds); ONE barrier +
// one vmcnt(0) per output tile, drained loads are a full tile old.
// Row sums accumulate in registers across tiles; one atomic round/block.
// Memsets fused into prep (5 dispatches -> 3).

#define BB 8192
#define DD 128
#define TM 128
#define TN 128
#define NJ 8

typedef __attribute__((ext_vector_type(8))) short short8;
typedef __attribute__((ext_vector_type(4))) float floatx4;

#define GLOBAL_AS __attribute__((address_space(1)))
#define LDS_AS    __attribute__((address_space(3)))

static __device__ __forceinline__ float wave_sum(float v) {
#pragma unroll
    for (int off = 32; off > 0; off >>= 1) v += __shfl_xor(v, off, 64);
    return v;
}

static __device__ __forceinline__ unsigned short f2bf(float f) {
    unsigned int u = __float_as_uint(f);
    return (unsigned short)((u + 0x7FFFu + ((u >> 16) & 1u)) >> 16);
}

// ---- prep: normalize rows (fp32) -> bf16 copies + 1/norm; zero denom/out --
__global__ __launch_bounds__(256) void prep_kernel(
    const float* __restrict__ zis, const float* __restrict__ zjs,
    unsigned short* __restrict__ Zib, unsigned short* __restrict__ Zjb,
    float* __restrict__ rni, float* __restrict__ rnj,
    float* __restrict__ denom, float* __restrict__ out, int nout)
{
    // fold the two hipMemsetAsync dispatches in here (4096 blocks x 2 floats)
    if (threadIdx.x < 2) denom[blockIdx.x * 2 + threadIdx.x] = 0.0f;
    if (blockIdx.x == 0 && (int)threadIdx.x < nout) out[threadIdx.x] = 0.0f;

    int wave = threadIdx.x >> 6, lane = threadIdx.x & 63;
    int row = blockIdx.x * 4 + wave;
    const float* src; unsigned short* dst; float* rn; int r;
    if (row < BB) { src = zis; dst = Zib; rn = rni; r = row; }
    else          { src = zjs; dst = Zjb; rn = rnj; r = row - BB; }
    float2 u = *(const float2*)(src + (size_t)r * DD + lane * 2);
    float s = wave_sum(u.x * u.x + u.y * u.y);
    float sc = 1.0f / sqrtf(s);
    if (lane == 0) rn[r] = sc;
    ushort2 o; o.x = f2bf(u.x * sc); o.y = f2bf(u.y * sc);
    *(ushort2*)(dst + (size_t)r * DD + lane * 2) = o;
}

// ---- j-streaming MFMA kernel --------------------------------------------
// Block: 256 thr (4 waves, 2x2), owns 128 A-rows, streams 8 B-tiles of 128
// cols x K=128. LDS: B double-buffer only (2 x 32 KB = 64 KB).
// LDS B layout: row n (128 x 256 B), 16-B slot p; logical k-slot s stored at
// p = s ^ (n & 15). ds_read_b128 frag fetch: lanes -> 2 per 16-B granule
// (2-way = free, m136). global_load_lds dest is linear (lane*16); the
// swizzle is applied on the per-lane GLOBAL source address (rule #21).
__global__ __launch_bounds__(256, 2) void mfma_tile_kernel(
    const unsigned short* __restrict__ Zjb,   // A: zj normalized (rows i)
    const unsigned short* __restrict__ Zib,   // B: zi normalized (cols j)
    const int* __restrict__ ilab, const int* __restrict__ jlab,
    float* __restrict__ denom)
{
    __shared__ __align__(16) unsigned short Bt[2][TN * DD];   // 64 KB

    int tid  = threadIdx.x;
    int lane = tid & 63, wave = tid >> 6;
    int wm = wave >> 1, wn = wave & 1;        // 2x2 wave grid, 64x64 each
    int quad = lane >> 4, l15 = lane & 15;
    int i0    = blockIdx.y * TM;
    int jbase = blockIdx.x * (NJ * TN);

    // ---- A fragments -> registers (once per block, from L2) -------------
    // af[mt][ks]: row = wm*64 + mt*16 + l15, k = ks*32 + quad*8  (64 VGPR)
    short8 af[4][4];
#pragma unroll
    for (int mt = 0; mt < 4; ++mt)
#pragma unroll
        for (int ks = 0; ks < 4; ++ks)
            af[mt][ks] = *(const short8*)(Zjb
                + (size_t)(i0 + wm * 64 + mt * 16 + l15) * DD
                + ks * 32 + quad * 8);

    // j-labels for my 16 output rows (uniform across l15)
    int jlv[4][4];
#pragma unroll
    for (int mt = 0; mt < 4; ++mt)
#pragma unroll
        for (int r = 0; r < 4; ++r)
            jlv[mt][r] = jlab[i0 + wm * 64 + mt * 16 + quad * 4 + r];

    // ---- staging: 32 regions x 1 KB; wave-uniform LDS base + lane*16 ----
    int rl = lane >> 4, p = lane & 15;
    auto stage = [&](int t) {
        const unsigned short* src = Zib + (size_t)(jbase + t * TN) * DD;
        unsigned short* lb = &Bt[t & 1][0];
#pragma unroll
        for (int u = 0; u < 8; ++u) {
            int g = wave * 8 + u;                 // region 0..31
            int grow = g * 4 + rl;                // B-tile row 0..127
            int gslot = p ^ (grow & 15);          // inverse swizzle on source
            const unsigned short* gp = src + (size_t)grow * DD + gslot * 8;
            unsigned short* lp = lb + g * 512;    // wave-uniform base
            __builtin_amdgcn_global_load_lds((const GLOBAL_AS void*)gp,
                                             (LDS_AS void*)lp, 16, 0, 0);
        }
    };

    float rs[4][4];
#pragma unroll
    for (int mt = 0; mt < 4; ++mt)
#pragma unroll
        for (int r = 0; r < 4; ++r) rs[mt][r] = 0.0f;

    stage(0);
    stage(1);
    // stage(1)'s 8 loads are the youngest VMEM ops -> vmcnt(8) guarantees
    // stage(0) (and everything older) has landed; stage(1) stays in flight.
    asm volatile("s_waitcnt vmcnt(8)" ::: "memory");
    __builtin_amdgcn_s_barrier();

    for (int t = 0; t < NJ; ++t) {
        // i-labels for my 4 column groups of this tile
        int ilv[4];
#pragma unroll
        for (int nt = 0; nt < 4; ++nt)
            ilv[nt] = ilab[jbase + t * TN + wn * 64 + nt * 16 + l15];

        const unsigned short* bb = &Bt[t & 1][0];
        floatx4 acc[4][4];

        __builtin_amdgcn_s_setprio(1);
#pragma unroll
        for (int ks = 0; ks < 4; ++ks) {
            short8 bfr[4];
#pragma unroll
            for (int nt = 0; nt < 4; ++nt) {
                int n = wn * 64 + nt * 16 + l15;
                int ps = (((ks << 2) | quad) ^ l15) << 3;  // phys slot * 8
                bfr[nt] = *(const short8*)(bb + n * DD + ps);
            }
            if (ks == 0) {
                floatx4 zz = (floatx4){0.f, 0.f, 0.f, 0.f};
#pragma unroll
                for (int mt = 0; mt < 4; ++mt)
#pragma unroll
                    for (int nt = 0; nt < 4; ++nt)
                        acc[mt][nt] = __builtin_amdgcn_mfma_f32_16x16x32_bf16(
                            af[mt][0], bfr[nt], zz, 0, 0, 0);
            } else {
#pragma unroll
                for (int mt = 0; mt < 4; ++mt)
#pragma unroll
                    for (int nt = 0; nt < 4; ++nt)
                        acc[mt][nt] = __builtin_amdgcn_mfma_f32_16x16x32_bf16(
                            af[mt][ks], bfr[nt], acc[mt][nt], 0, 0, 0);
            }
        }
        __builtin_amdgcn_s_setprio(0);

        // One drain+barrier per tile. The loads drained here (stage t+1)
        // were issued a full tile ago -> near-zero stall. stage(t+2) then
        // overlaps this tile's epilogue + next tile's compute.
        if (t + 1 < NJ) {
            asm volatile("s_waitcnt vmcnt(0)" ::: "memory");
            __builtin_amdgcn_s_barrier();
            if (t + 2 < NJ) stage(t + 2);
        }

        // epilogue: e = exp(10*c - 10), mask, accumulate in registers.
        // C/D layout: col = l15, row = quad*4 + r.
#pragma unroll
        for (int mt = 0; mt < 4; ++mt) {
#pragma unroll
            for (int r = 0; r < 4; ++r) {
                int jr = jlv[mt][r];
                float s = rs[mt][r];
#pragma unroll
                for (int nt = 0; nt < 4; ++nt) {
                    float e = __expf(fmaf(acc[mt][nt][r], 10.0f, -10.0f));
                    s += (ilv[nt] != jr) ? e : 0.0f;
                }
                rs[mt][r] = s;
            }
        }
    }

    // ---- final reduce over l15 (16 lanes) + one atomic round per block ---
#pragma unroll
    for (int mt = 0; mt < 4; ++mt) {
#pragma unroll
        for (int r = 0; r < 4; ++r) {
            float v = rs[mt][r];
            v += __shfl_xor(v, 1, 64);
            v += __shfl_xor(v, 2, 64);
            v += __shfl_xor(v, 4, 64);
            v += __shfl_xor(v, 8, 64);
            if (l15 == 0)
                atomicAdd(&denom[i0 + wm * 64 + mt * 16 + quad * 4 + r], v);
        }
    }
}

// ---- fused pos + finalize (512 blocks, 4 rows/wave, 1 atomic/block) ------
__global__ __launch_bounds__(256) void posfinal_kernel(
    const float* __restrict__ zis, const float* __restrict__ zjs,
    const float* __restrict__ rni, const float* __restrict__ rnj,
    const float* __restrict__ denom, const float* __restrict__ wts,
    const int* __restrict__ idxp, float* __restrict__ out)
{
    int wave = threadIdx.x >> 6, lane = threadIdx.x & 63;
    int idx = idxp[0];
    float ll = 0.0f;
#pragma unroll
    for (int t = 0; t < 4; ++t) {
        int i = blockIdx.x * 16 + wave * 4 + t;
        int j = idx + i;
        float2 a  = *(const float2*)(zjs + (size_t)i * DD + lane * 2);
        float2 b2 = *(const float2*)(zis + (size_t)j * DD + lane * 2);
        float s = wave_sum(a.x * b2.x + a.y * b2.y);
        if (lane == 0) {
            float p = s * rni[j] * rnj[i] * 10.0f;
            float l = 10.0f + logf(__expf(p - 10.0f) + denom[i]) - p;
            float w = wts[j];
            ll += (l * w) / w;    // faithful to reference's weighted mean
        }
    }
    __shared__ float part[4];
    if (lane == 0) part[wave] = ll;
    __syncthreads();
    if (threadIdx.x == 0)
        atomicAdd(out, (part[0] + part[1] + part[2] + part[3]) * (1.0f / BB));
}

// ---- launch --------------------------------------------------------------
extern "C" void kernel_launch(void* const* d_in, const int* in_sizes, int n_in,
                              void* d_out, int out_size, void* d_ws, size_t ws_size,
                              hipStream_t stream) {
    const float* zis = (const float*)d_in[0];
    const float* zjs = (const float*)d_in[1];
    const int* ilab = (const int*)d_in[2];
    const int* jlab = (const int*)d_in[3];
    const float* wts = (const float*)d_in[4];
    const int* idxp = (const int*)d_in[5];
    float* out = (float*)d_out;

    float* rni   = (float*)d_ws;
    float* rnj   = rni + BB;
    float* denom = rnj + BB;
    unsigned short* Zib = (unsigned short*)(denom + BB);  // [BB][DD] bf16
    unsigned short* Zjb = Zib + (size_t)BB * DD;

    prep_kernel<<<2 * BB / 4, 256, 0, stream>>>(
        zis, zjs, Zib, Zjb, rni, rnj, denom, out, out_size);
    mfma_tile_kernel<<<dim3(BB / (NJ * TN), BB / TM), 256, 0, stream>>>(
        Zjb, Zib, ilab, jlab, denom);
    posfinal_kernel<<<BB / 16, 256, 0, stream>>>(
        zis, zjs, rni, rnj, denom, wts, idxp, out);
}